// Round 22
// baseline (252.006 us; speedup 1.0000x reference)
//
#include <hip/hip_runtime.h>
#include <cstdint>

#define TSIZE (1u << 19)
#define MASKU (TSIZE - 1u)
#define P1U 2654435761u

// r22 = r21 + counter padding (one counter per 64B line):
//  - scatter was ~85us for ~4M line-events (20x its event floor); after r13/
//    r14/r15 eliminated NT/capacity/bounce, the remaining suspect is L2
//    atomic serialization on shared counter LINES (16 counters/line, 2M
//    atomics). Pad cnt index <<4 so each counter owns a line.
//  - main at its modeled service ceiling (~0.25M line-events/us, r20/r21).
//  - embed: r20 numerics; coalesced out-stores (r21); per-XCD scatter (r15);
//    AoS float4 recs (r11); NO nontemporal (r13); ws = 1 GiB (r14).
#define CBINS_X 128
#define NCHILD (CBINS_X * CBINS_X)      // 16384 children (16-px bins)
#define XPART 8
#define CAPX 32
#define SLOTS ((size_t)XPART * NCHILD * CAPX)   // 4,194,304 slots (67 MB)
#define CPAD 16                          // counters padded to 64B lines

// ---------------- embed core: compute feat[32] (no store) -------------------
__device__ __forceinline__ void embed_core(float2 xv,
                                           const float* __restrict__ tables,
                                           float* __restrict__ feat) {
  constexpr int RESV[16] = {16, 22, 30, 42, 58, 80, 111, 153,
                            212, 294, 406, 561, 776, 1072, 1482, 2047};
  const float2* tabs = reinterpret_cast<const float2*>(tables);

  float w0a[16], w1a[16];
  int baseA[12];
  uint32_t hidx[4][4];

#pragma unroll
  for (int l = 0; l < 16; ++l) {
    const int res = RESV[l];
    const float gs = (float)(2048.0 / (double)res);   // ref's rounded gs
    const float inv = (float)res * 0.00048828125f;    // res*2^-11, EXACT
    float f0 = floorf(xv.x * inv);
    float f1 = floorf(xv.y * inv);
    float g0 = f0 * gs;
    float g1 = f1 * gs;
    w0a[l] = (xv.x - g0) * inv;
    w1a[l] = (xv.y - g1) * inv;
    if (l < 12) {
      baseA[l] = (int)f0 * res + (int)f1;
    } else {
      uint32_t u0 = (uint32_t)(int)f0;
      uint32_t u1m = (uint32_t)(int)f1 * P1U;
      hidx[l - 12][0] = (u0 ^ u1m) & MASKU;
      hidx[l - 12][1] = (u0 ^ (u1m + P1U)) & MASKU;
      hidx[l - 12][2] = ((u0 + 1u) ^ u1m) & MASKU;
      hidx[l - 12][3] = ((u0 + 1u) ^ (u1m + P1U)) & MASKU;
    }
  }

  float2 eh[4][4];
#pragma unroll
  for (int l = 0; l < 4; ++l) {
    const float2* tab = tabs + (size_t)(12 + l) * TSIZE;
    eh[l][0] = tab[hidx[l][0]];
    eh[l][1] = tab[hidx[l][1]];
    eh[l][2] = tab[hidx[l][2]];
    eh[l][3] = tab[hidx[l][3]];
  }
  float4 lo[12], hi[12];
#pragma unroll
  for (int l = 0; l < 12; ++l) {
    const float2* tab = tabs + (size_t)l * TSIZE;
    lo[l] = *reinterpret_cast<const float4*>(tab + baseA[l]);
    hi[l] = *reinterpret_cast<const float4*>(tab + baseA[l] + RESV[l]);
  }

  __builtin_amdgcn_sched_barrier(0);   // all loads issued before lerps

#pragma unroll
  for (int l = 0; l < 12; ++l) {
    float w0 = w0a[l], w1 = w1a[l];
    float omw0 = 1.0f - w0, omw1 = 1.0f - w1;
    float c0x = lo[l].x * omw1 + lo[l].z * w1;
    float c0y = lo[l].y * omw1 + lo[l].w * w1;
    float c1x = hi[l].x * omw1 + hi[l].z * w1;
    float c1y = hi[l].y * omw1 + hi[l].w * w1;
    feat[2 * l]     = c0x * omw0 + c1x * w0;
    feat[2 * l + 1] = c0y * omw0 + c1y * w0;
  }
#pragma unroll
  for (int l = 0; l < 4; ++l) {
    float w0 = w0a[12 + l], w1 = w1a[12 + l];
    float omw0 = 1.0f - w0, omw1 = 1.0f - w1;
    float c0x = eh[l][0].x * omw1 + eh[l][1].x * w1;
    float c0y = eh[l][0].y * omw1 + eh[l][1].y * w1;
    float c1x = eh[l][2].x * omw1 + eh[l][3].x * w1;
    float c1y = eh[l][2].y * omw1 + eh[l][3].y * w1;
    feat[24 + 2 * l]     = c0x * omw0 + c1x * w0;
    feat[24 + 2 * l + 1] = c0y * omw0 + c1y * w0;
  }
}

// plain per-lane store (ovf / fallback paths)
__device__ __forceinline__ void embed_point(float2 xv, int orig,
                                            const float* __restrict__ tables,
                                            float* __restrict__ out) {
  float feat[32];
  embed_core(xv, tables, feat);
  float4* o = reinterpret_cast<float4*>(out) + (size_t)orig * 8;
#pragma unroll
  for (int j = 0; j < 8; ++j) {
    o[j] = make_float4(feat[4 * j], feat[4 * j + 1], feat[4 * j + 2], feat[4 * j + 3]);
  }
}

// ---------------- per-XCD partitioned capacity-bin sort ---------------------

__device__ __forceinline__ int child_of(float2 xv) {
  int bx = min((int)(xv.x * 0.0625f), CBINS_X - 1);   // 16-px coords
  int by = min((int)(xv.y * 0.0625f), CBINS_X - 1);
  int parent = ((bx >> 1) << 6) + (by >> 1);          // 64x64 parents
  int quad = ((bx & 1) << 1) + (by & 1);
  return (parent << 2) + quad;
}

__global__ __launch_bounds__(256) void scatter_px(
    const float2* __restrict__ xs, int* __restrict__ cnt,
    float4* __restrict__ recs,
    int* __restrict__ ovf, int* __restrict__ ovf_cnt, int B) {
  int p = blockIdx.x * 256 + threadIdx.x;
  if (p >= B) return;
  int part = blockIdx.x & 7;              // this block's XCD (round-robin map)
  float2 xv = xs[p];
  int pc = part * NCHILD + child_of(xv);  // (xcd, child) composite
  int pos = atomicAdd(&cnt[(size_t)pc * CPAD], 1);   // 1 counter per 64B line
  if (pos < CAPX) {
    recs[(size_t)pc * CAPX + pos] =       // record line local to this XCD
        make_float4(xv.x, xv.y, __int_as_float(p), 0.0f);
  } else {
    int o = atomicAdd(ovf_cnt, 1);
    ovf[o] = p;  // ovf capacity == B: can never overflow
  }
}

// main: block = one child; compacted lanes; wave-cooperative coalesced stores
__global__ __launch_bounds__(256, 1) void hashenc_cmp(
    const float4* __restrict__ recs, const int* __restrict__ cnt,
    const float* __restrict__ tables, float* __restrict__ out) {
  __shared__ int pre[9];
  __shared__ float sf[256 * 33];          // 33 KB: per-lane feat, pad 33
  int bid = blockIdx.x;
  int nb = gridDim.x;                     // 16384, divisible by 8
  int chunk = nb >> 3;                    // 2048 children per XCD slab
  int child = (bid & 7) * chunk + (bid >> 3);   // XCD k owns slab k (spatial)
  if (threadIdx.x == 0) {
    int s = 0;
    pre[0] = 0;
#pragma unroll
    for (int k = 0; k < XPART; ++k) {
      s += min(cnt[(size_t)(k * NCHILD + child) * CPAD], CAPX);
      pre[k + 1] = s;
    }
  }
  __syncthreads();
  int total = pre[8];
  int wbase = threadIdx.x & ~63;          // wave start (0,64,128,192)
  if (wbase >= total) return;             // whole-wave uniform exit
  int lane = threadIdx.x & 63;
  int nact = min(total - wbase, 64);      // active lanes are a wave PREFIX
  bool active = lane < nact;

  float feat[32];
  int orig = 0;
  if (active) {
    int i = threadIdx.x;
    int k = 0;
#pragma unroll
    for (int kk = 1; kk < XPART; ++kk) k = (i >= pre[kk]) ? kk : k;
    int j = i - pre[k];
    float4 r = recs[((size_t)(k * NCHILD + child)) * CAPX + j];
    orig = __float_as_int(r.z);
    embed_core(make_float2(r.x, r.y), tables, feat);
  }

  // stage feat to LDS (stride 33: 2-way bank alias = free)
  float* myf = &sf[threadIdx.x * 33];
#pragma unroll
  for (int f = 0; f < 32; ++f) myf[f] = feat[f];
  __builtin_amdgcn_sched_barrier(0);      // in-wave: writes before reads

  // cooperative store: 4 lanes emit one point's 64B line per instruction
  float* wf = &sf[wbase * 33];
  int sub = lane & 3;
#pragma unroll
  for (int jj = 0; jj < 4; ++jj) {
    int p = jj * 16 + (lane >> 2);        // point index within wave
    int op = __builtin_amdgcn_ds_bpermute(p << 2, orig);
    if (p < nact) {
#pragma unroll
      for (int h = 0; h < 2; ++h) {
        const float* src = &wf[p * 33 + h * 16 + sub * 4];
        float4 v = make_float4(src[0], src[1], src[2], src[3]);
        *reinterpret_cast<float4*>(out + (size_t)op * 32 + h * 16 + sub * 4) = v;
      }
    }
  }
}

__global__ __launch_bounds__(256) void ovf_kernel(
    const float2* __restrict__ xs, const int* __restrict__ ovf,
    const int* __restrict__ ovf_cnt, const float* __restrict__ tables,
    float* __restrict__ out) {
  int n = *ovf_cnt;
  for (int i = blockIdx.x * 256 + threadIdx.x; i < n; i += gridDim.x * 256) {
    int p = ovf[i];
    embed_point(xs[p], p, tables, out);
  }
}

// ---------------- unsorted fallback -----------------------------------------

__global__ __launch_bounds__(256, 2) void hashenc_plain(
    const float2* __restrict__ xs, const float* __restrict__ tables,
    float* __restrict__ out, int B) {
  int p = blockIdx.x * 256 + threadIdx.x;
  if (p >= B) return;
  embed_point(xs[p], p, tables, out);
}

// ---------------- launch ----------------------------------------------------

extern "C" void kernel_launch(void* const* d_in, const int* in_sizes, int n_in,
                              void* d_out, int out_size, void* d_ws, size_t ws_size,
                              hipStream_t stream) {
  const float2* xs = (const float2*)d_in[0];
  const float* tables = (const float*)d_in[1];
  float* out = (float*)d_out;
  int B = in_sizes[0] / 2;
  int blocks = (B + 255) / 256;
  char* ws = (char*)d_ws;

  // layout: recs (16B*SLOTS = 67MB) | ovf (4B*B) | cnt (padded, 8MB) | ovf_cnt
  size_t c_recs = 0;
  size_t c_ovf = c_recs + SLOTS * 16;
  size_t c_cnt = c_ovf + (size_t)B * 4;
  size_t cnt_bytes = (size_t)XPART * NCHILD * CPAD * 4;   // 8 MB
  size_t c_ocnt = c_cnt + cnt_bytes;
  size_t need = c_ocnt + 64;

  bool grid_ok = (blocks & 7) == 0;
  if (grid_ok && ws_size >= need) {
    float4* recs = (float4*)(ws + c_recs);
    int* ovf = (int*)(ws + c_ovf);
    int* cnt = (int*)(ws + c_cnt);
    int* ovf_cnt = (int*)(ws + c_ocnt);
    (void)hipMemsetAsync(cnt, 0, cnt_bytes + 64, stream);  // cnt + ovf_cnt
    hipLaunchKernelGGL(scatter_px, dim3(blocks), dim3(256), 0, stream,
                       xs, cnt, recs, ovf, ovf_cnt, B);
    hipLaunchKernelGGL(hashenc_cmp, dim3(NCHILD), dim3(256), 0, stream,
                       recs, cnt, tables, out);
    hipLaunchKernelGGL(ovf_kernel, dim3(32), dim3(256), 0, stream,
                       xs, ovf, ovf_cnt, tables, out);
  } else {
    hipLaunchKernelGGL(hashenc_plain, dim3(blocks), dim3(256), 0, stream,
                       xs, tables, out, B);
  }
}

// Round 23
// 238.687 us; speedup vs baseline: 1.0558x; 1.0558x over previous
//
#include <hip/hip_runtime.h>
#include <cstdint>

#define TSIZE (1u << 19)
#define MASKU (TSIZE - 1u)
#define P1U 2654435761u

// FINAL (r21 revert, best = 240.3us): r22's counter-padding regressed (252).
//  - main (~145us): at L2 request-service ceiling (~0.25M line-events/us,
//    ~15.6 req/cy/XCD): ~35M events, 70% irreducibly-random hash gathers.
//    Exonerated: waves (r16), span (r18), per-thread pts (r17), occupancy/
//    MLP (r19), VALU (r20). Wins: spatial sort (r4..), coalesced stores (r21).
//  - scatter (~85us): HBM RMW floor on 67MB recs (2M scattered 16B stores).
//    Exonerated: NT (r13), region size (r14), XCD bounce (r15 fixed it),
//    atomic line conflicts (r22).
//  - numerics: RES[15]=2047 (r2); searchsorted==identity; mul-by-exact-inv
//    (r20); absmax 4.77e-7 vs thr 1.99e-6.
#define CBINS_X 128
#define NCHILD (CBINS_X * CBINS_X)      // 16384 children (16-px bins)
#define XPART 8
#define CAPX 32
#define SLOTS ((size_t)XPART * NCHILD * CAPX)   // 4,194,304 slots (67 MB)

// ---------------- embed core: compute feat[32] (no store) -------------------
__device__ __forceinline__ void embed_core(float2 xv,
                                           const float* __restrict__ tables,
                                           float* __restrict__ feat) {
  constexpr int RESV[16] = {16, 22, 30, 42, 58, 80, 111, 153,
                            212, 294, 406, 561, 776, 1072, 1482, 2047};
  const float2* tabs = reinterpret_cast<const float2*>(tables);

  float w0a[16], w1a[16];
  int baseA[12];
  uint32_t hidx[4][4];

#pragma unroll
  for (int l = 0; l < 16; ++l) {
    const int res = RESV[l];
    const float gs = (float)(2048.0 / (double)res);   // ref's rounded gs
    const float inv = (float)res * 0.00048828125f;    // res*2^-11, EXACT
    float f0 = floorf(xv.x * inv);
    float f1 = floorf(xv.y * inv);
    float g0 = f0 * gs;
    float g1 = f1 * gs;
    w0a[l] = (xv.x - g0) * inv;
    w1a[l] = (xv.y - g1) * inv;
    if (l < 12) {
      baseA[l] = (int)f0 * res + (int)f1;
    } else {
      uint32_t u0 = (uint32_t)(int)f0;
      uint32_t u1m = (uint32_t)(int)f1 * P1U;
      hidx[l - 12][0] = (u0 ^ u1m) & MASKU;
      hidx[l - 12][1] = (u0 ^ (u1m + P1U)) & MASKU;
      hidx[l - 12][2] = ((u0 + 1u) ^ u1m) & MASKU;
      hidx[l - 12][3] = ((u0 + 1u) ^ (u1m + P1U)) & MASKU;
    }
  }

  float2 eh[4][4];
#pragma unroll
  for (int l = 0; l < 4; ++l) {
    const float2* tab = tabs + (size_t)(12 + l) * TSIZE;
    eh[l][0] = tab[hidx[l][0]];
    eh[l][1] = tab[hidx[l][1]];
    eh[l][2] = tab[hidx[l][2]];
    eh[l][3] = tab[hidx[l][3]];
  }
  float4 lo[12], hi[12];
#pragma unroll
  for (int l = 0; l < 12; ++l) {
    const float2* tab = tabs + (size_t)l * TSIZE;
    lo[l] = *reinterpret_cast<const float4*>(tab + baseA[l]);
    hi[l] = *reinterpret_cast<const float4*>(tab + baseA[l] + RESV[l]);
  }

  __builtin_amdgcn_sched_barrier(0);   // all loads issued before lerps

#pragma unroll
  for (int l = 0; l < 12; ++l) {
    float w0 = w0a[l], w1 = w1a[l];
    float omw0 = 1.0f - w0, omw1 = 1.0f - w1;
    float c0x = lo[l].x * omw1 + lo[l].z * w1;
    float c0y = lo[l].y * omw1 + lo[l].w * w1;
    float c1x = hi[l].x * omw1 + hi[l].z * w1;
    float c1y = hi[l].y * omw1 + hi[l].w * w1;
    feat[2 * l]     = c0x * omw0 + c1x * w0;
    feat[2 * l + 1] = c0y * omw0 + c1y * w0;
  }
#pragma unroll
  for (int l = 0; l < 4; ++l) {
    float w0 = w0a[12 + l], w1 = w1a[12 + l];
    float omw0 = 1.0f - w0, omw1 = 1.0f - w1;
    float c0x = eh[l][0].x * omw1 + eh[l][1].x * w1;
    float c0y = eh[l][0].y * omw1 + eh[l][1].y * w1;
    float c1x = eh[l][2].x * omw1 + eh[l][3].x * w1;
    float c1y = eh[l][2].y * omw1 + eh[l][3].y * w1;
    feat[24 + 2 * l]     = c0x * omw0 + c1x * w0;
    feat[24 + 2 * l + 1] = c0y * omw0 + c1y * w0;
  }
}

// plain per-lane store (ovf / fallback paths)
__device__ __forceinline__ void embed_point(float2 xv, int orig,
                                            const float* __restrict__ tables,
                                            float* __restrict__ out) {
  float feat[32];
  embed_core(xv, tables, feat);
  float4* o = reinterpret_cast<float4*>(out) + (size_t)orig * 8;
#pragma unroll
  for (int j = 0; j < 8; ++j) {
    o[j] = make_float4(feat[4 * j], feat[4 * j + 1], feat[4 * j + 2], feat[4 * j + 3]);
  }
}

// ---------------- per-XCD partitioned capacity-bin sort ---------------------

__device__ __forceinline__ int child_of(float2 xv) {
  int bx = min((int)(xv.x * 0.0625f), CBINS_X - 1);   // 16-px coords
  int by = min((int)(xv.y * 0.0625f), CBINS_X - 1);
  int parent = ((bx >> 1) << 6) + (by >> 1);          // 64x64 parents
  int quad = ((bx & 1) << 1) + (by & 1);
  return (parent << 2) + quad;
}

__global__ __launch_bounds__(256) void scatter_px(
    const float2* __restrict__ xs, int* __restrict__ cnt,
    float4* __restrict__ recs,
    int* __restrict__ ovf, int* __restrict__ ovf_cnt, int B) {
  int p = blockIdx.x * 256 + threadIdx.x;
  if (p >= B) return;
  int part = blockIdx.x & 7;              // this block's XCD (round-robin map)
  float2 xv = xs[p];
  int pc = part * NCHILD + child_of(xv);  // (xcd, child) composite
  int pos = atomicAdd(&cnt[pc], 1);       // counter line local to this XCD
  if (pos < CAPX) {
    recs[(size_t)pc * CAPX + pos] =       // record line local to this XCD
        make_float4(xv.x, xv.y, __int_as_float(p), 0.0f);
  } else {
    int o = atomicAdd(ovf_cnt, 1);
    ovf[o] = p;  // ovf capacity == B: can never overflow
  }
}

// main: block = one child; compacted lanes; wave-cooperative coalesced stores
__global__ __launch_bounds__(256, 1) void hashenc_cmp(
    const float4* __restrict__ recs, const int* __restrict__ cnt,
    const float* __restrict__ tables, float* __restrict__ out) {
  __shared__ int pre[9];
  __shared__ float sf[256 * 33];          // 33 KB: per-lane feat, pad 33
  int bid = blockIdx.x;
  int nb = gridDim.x;                     // 16384, divisible by 8
  int chunk = nb >> 3;                    // 2048 children per XCD slab
  int child = (bid & 7) * chunk + (bid >> 3);   // XCD k owns slab k (spatial)
  if (threadIdx.x == 0) {
    int s = 0;
    pre[0] = 0;
#pragma unroll
    for (int k = 0; k < XPART; ++k) {
      s += min(cnt[k * NCHILD + child], CAPX);
      pre[k + 1] = s;
    }
  }
  __syncthreads();
  int total = pre[8];
  int wbase = threadIdx.x & ~63;          // wave start (0,64,128,192)
  if (wbase >= total) return;             // whole-wave uniform exit
  int lane = threadIdx.x & 63;
  int nact = min(total - wbase, 64);      // active lanes are a wave PREFIX
  bool active = lane < nact;

  float feat[32];
  int orig = 0;
  if (active) {
    int i = threadIdx.x;
    int k = 0;
#pragma unroll
    for (int kk = 1; kk < XPART; ++kk) k = (i >= pre[kk]) ? kk : k;
    int j = i - pre[k];
    float4 r = recs[((size_t)(k * NCHILD + child)) * CAPX + j];
    orig = __float_as_int(r.z);
    embed_core(make_float2(r.x, r.y), tables, feat);
  }

  // stage feat to LDS (stride 33: 2-way bank alias = free)
  float* myf = &sf[threadIdx.x * 33];
#pragma unroll
  for (int f = 0; f < 32; ++f) myf[f] = feat[f];
  __builtin_amdgcn_sched_barrier(0);      // in-wave: writes before reads

  // cooperative store: 4 lanes emit one point's 64B line per instruction
  float* wf = &sf[wbase * 33];
  int sub = lane & 3;
#pragma unroll
  for (int jj = 0; jj < 4; ++jj) {
    int p = jj * 16 + (lane >> 2);        // point index within wave
    int op = __builtin_amdgcn_ds_bpermute(p << 2, orig);
    if (p < nact) {
#pragma unroll
      for (int h = 0; h < 2; ++h) {
        const float* src = &wf[p * 33 + h * 16 + sub * 4];
        float4 v = make_float4(src[0], src[1], src[2], src[3]);
        *reinterpret_cast<float4*>(out + (size_t)op * 32 + h * 16 + sub * 4) = v;
      }
    }
  }
}

__global__ __launch_bounds__(256) void ovf_kernel(
    const float2* __restrict__ xs, const int* __restrict__ ovf,
    const int* __restrict__ ovf_cnt, const float* __restrict__ tables,
    float* __restrict__ out) {
  int n = *ovf_cnt;
  for (int i = blockIdx.x * 256 + threadIdx.x; i < n; i += gridDim.x * 256) {
    int p = ovf[i];
    embed_point(xs[p], p, tables, out);
  }
}

// ---------------- unsorted fallback -----------------------------------------

__global__ __launch_bounds__(256, 2) void hashenc_plain(
    const float2* __restrict__ xs, const float* __restrict__ tables,
    float* __restrict__ out, int B) {
  int p = blockIdx.x * 256 + threadIdx.x;
  if (p >= B) return;
  embed_point(xs[p], p, tables, out);
}

// ---------------- launch ----------------------------------------------------

extern "C" void kernel_launch(void* const* d_in, const int* in_sizes, int n_in,
                              void* d_out, int out_size, void* d_ws, size_t ws_size,
                              hipStream_t stream) {
  const float2* xs = (const float2*)d_in[0];
  const float* tables = (const float*)d_in[1];
  float* out = (float*)d_out;
  int B = in_sizes[0] / 2;
  int blocks = (B + 255) / 256;
  char* ws = (char*)d_ws;

  // layout: recs (16B*SLOTS = 67MB) | ovf (4B*B) | cnt (4B*8*NCHILD = 512KB)
  //         | ovf_cnt (+pad)
  size_t c_recs = 0;
  size_t c_ovf = c_recs + SLOTS * 16;
  size_t c_cnt = c_ovf + (size_t)B * 4;
  size_t c_ocnt = c_cnt + (size_t)XPART * NCHILD * 4;
  size_t need = c_ocnt + 64;

  bool grid_ok = (blocks & 7) == 0;
  if (grid_ok && ws_size >= need) {
    float4* recs = (float4*)(ws + c_recs);
    int* ovf = (int*)(ws + c_ovf);
    int* cnt = (int*)(ws + c_cnt);
    int* ovf_cnt = (int*)(ws + c_ocnt);
    (void)hipMemsetAsync(cnt, 0, (size_t)XPART * NCHILD * 4 + 64, stream);
    hipLaunchKernelGGL(scatter_px, dim3(blocks), dim3(256), 0, stream,
                       xs, cnt, recs, ovf, ovf_cnt, B);
    hipLaunchKernelGGL(hashenc_cmp, dim3(NCHILD), dim3(256), 0, stream,
                       recs, cnt, tables, out);
    hipLaunchKernelGGL(ovf_kernel, dim3(32), dim3(256), 0, stream,
                       xs, ovf, ovf_cnt, tables, out);
  } else {
    hipLaunchKernelGGL(hashenc_plain, dim3(blocks), dim3(256), 0, stream,
                       xs, tables, out, B);
  }
}